// Round 26
// baseline (134.997 us; speedup 1.0000x reference)
//
#include <hip/hip_runtime.h>
#include <math.h>

#define BB 16
#define CC 32
#define OO 32
#define HH 256
#define WW 256
#define HW (HH * WW)
#define PD 8
#define HP (HH + 2 * PD)      // 272
#define WP (WW + 2 * PD)      // 272
#define NEMAX 36
#define NE21 21               // corner count for sigma=1-class offsets

// mix8 window geometry: block = 16 rows x 64 px; shifts |Sy|,|Sx| <= 7
#define WROWS 30              // 16 + 2*7
#define WCOLS 80              // 64 + 2*7
#define RUNITS 320            // 16B units per window row (80 px * 4)
#define WUNITS (WROWS * RUNITS)   // 9600 units = 153,600 B

typedef __attribute__((ext_vector_type(8))) short bf16x8;
typedef __attribute__((ext_vector_type(4))) float f32x4;
typedef __attribute__((ext_vector_type(4))) unsigned short us4;
typedef __attribute__((ext_vector_type(8))) unsigned short us8;

__device__ __forceinline__ unsigned short f2bf(float f) {
    unsigned u = __float_as_uint(f);
    u += 0x7fffu + ((u >> 16) & 1u);     // round-to-nearest-even
    return (unsigned short)(u >> 16);
}
__device__ __forceinline__ float bf2f(unsigned short v) {
    return __uint_as_float((unsigned)v << 16);
}

__device__ __forceinline__ void blur_wn(const float* sigma_p, float* wn) {
    const float sigma = sigma_p[0];
    const float inv2s2 = 1.0f / (2.0f * sigma * sigma);
    float e[5], s = 0.0f;
#pragma unroll
    for (int i = 0; i < 5; ++i) {
        float d = (float)(i - 2);
        e[i] = expf(-(d * d) * inv2s2);
        s += e[i];
    }
    const float inv_s = 1.0f / s;
#pragma unroll
    for (int i = 0; i < 5; ++i) wn[i] = e[i] * inv_s;
}

// ---------------------------------------------------------------------------
// Kernel 1: 5x5 separable Gaussian blur -> zero-padded channels-last bf16
//   xbt[b][y=h+PD][x=w+PD][c].
// R26: R25 body (all 24 row-loads issued before any vblur) with DEFAULT
// launch bounds — R25's (256,4) capped occupancy at 39% and exactly cancelled
// the ILP gain (R23: 28 VGPR/71% occ = R25: 56 VGPR/39% occ = 80us). At
// VGPR ~56 the HW allows 8 waves/SIMD and LDS allows 9 blocks/CU; only the
// launch bound was in the way.
// ---------------------------------------------------------------------------
#define LOADROWS(DST, IT)                                                         \
    {                                                                             \
        const int cl_ = ((IT) << 2) + wv;                                         \
        const float* xc_ = x + ((size_t)(b * CC + chalf * 16 + cl_) * HH) * WW + 4 * g; \
        _Pragma("unroll")                                                         \
        for (int k = 0; k < 6; ++k) {                                             \
            const int r_ = h0 - 2 + k;                                            \
            DST[k] = (r_ >= 0 && r_ < HH)                                         \
                   ? *reinterpret_cast<const f32x4*>(xc_ + r_ * WW)               \
                   : (f32x4){0.f, 0.f, 0.f, 0.f};                                 \
        }                                                                         \
    }

#define VBLUR(SRC, IT)                                                            \
    {                                                                             \
        const int cl_ = ((IT) << 2) + wv;                                         \
        _Pragma("unroll")                                                         \
        for (int j = 0; j < 2; ++j) {                                             \
            f32x4 a_ = {0.f, 0.f, 0.f, 0.f};                                      \
            _Pragma("unroll")                                                     \
            for (int i = 0; i < 5; ++i) {                                         \
                a_[0] = fmaf(wn[i], SRC[j + i][0], a_[0]);                        \
                a_[1] = fmaf(wn[i], SRC[j + i][1], a_[1]);                        \
                a_[2] = fmaf(wn[i], SRC[j + i][2], a_[2]);                        \
                a_[3] = fmaf(wn[i], SRC[j + i][3], a_[3]);                        \
            }                                                                     \
            us4 bv_;                                                              \
            bv_[0] = f2bf(a_[0]); bv_[1] = f2bf(a_[1]);                           \
            bv_[2] = f2bf(a_[2]); bv_[3] = f2bf(a_[3]);                           \
            *reinterpret_cast<us4*>(&vb[cl_][j][4 + 4 * g]) = bv_;                \
        }                                                                         \
    }

__global__ __launch_bounds__(256) void blur_t_kernel(const float* __restrict__ x,
                                                     const float* __restrict__ sigma_p,
                                                     unsigned short* __restrict__ xbt) {
    __shared__ __align__(16) unsigned short vb[16][2][268];   // 17,152 B
    const int t     = threadIdx.x;
    const int blk   = ((blockIdx.x & 7) << 9) + (blockIdx.x >> 3);  // 4096, chunk 512
    const int chalf = blk & 1;
    const int band  = (blk >> 1) & 127;
    const int b     = blk >> 8;
    const int h0    = band << 1;

    float wn[5];
    blur_wn(sigma_p, wn);

    unsigned short* xb_img = xbt + (size_t)b * (HP * WP * CC);

    // ---- halo zeroing (this block's 16 channels only; pair covers all) ----
    const us8 z8 = {0, 0, 0, 0, 0, 0, 0, 0};
    if (t < 64) {   // side halos of own 2 padded rows
        const int j  = t >> 5;
        const int px = (t >> 1) & 15;
        const int ch = t & 1;
        const int xx = (px < PD) ? px : px + WW;
        *reinterpret_cast<us8*>(xb_img + ((size_t)(h0 + PD + j) * WP + xx) * CC
                                + chalf * 16 + ch * 8) = z8;
    }
    if (h0 < PD) {           // bands 0..3: zero full padded rows y' = h0, h0+1
#pragma unroll
        for (int j2 = 0; j2 < 2; ++j2) {
            unsigned short* dst = xb_img + (size_t)(h0 + j2) * WP * CC + chalf * 16;
            for (int i = t; i < WP * 2; i += 256)
                *reinterpret_cast<us8*>(dst + (size_t)(i >> 1) * CC + (i & 1) * 8) = z8;
        }
    }
#pragma unroll
    for (int j2 = 0; j2 < 2; ++j2) {     // bottom padded rows
        if (h0 + j2 >= HH - PD) {
            unsigned short* dst = xb_img + (size_t)(h0 + j2 + 2 * PD) * WP * CC + chalf * 16;
            for (int i = t; i < WP * 2; i += 256)
                *reinterpret_cast<us8*>(dst + (size_t)(i >> 1) * CC + (i & 1) * 8) = z8;
        }
    }

    // edge zero cols: px {-2,-1,256,257} -> vb cols {2,3,260,261}
    if (t < 128) {
        const int cl = t >> 3;
        const int j  = (t >> 2) & 1;
        const int e_ = t & 3;
        const int idx = (e_ < 2) ? (2 + e_) : (258 + e_);
        vb[cl][j][idx] = 0;
    }

    // ---- phase 1: vertical blur, ALL loads issued before any use ----
    const int g  = t & 63;          // px group of 4
    const int wv = t >> 6;          // wave 0..3
    {
        f32x4 V[4][6];
#pragma unroll
        for (int it = 0; it < 4; ++it) LOADROWS(V[it], it);
#pragma unroll
        for (int it = 0; it < 4; ++it) VBLUR(V[it], it);
    }
    __syncthreads();

    // ---- phase 2: horizontal blur, 8 ch x 4 px x 1 row per thread ----
    const int cu8 = t & 1;
    const int p4  = (t >> 1) & 63;
    const int j   = t >> 7;
    const int P   = p4 << 2;
    const int cl0 = cu8 << 3;

    us8 o[4];                        // o[d] = 8 channels at px P+d
#pragma unroll
    for (int cc = 0; cc < 8; ++cc) {
        const unsigned short* vp = &vb[cl0 + cc][j][P];
        us4 r0 = *reinterpret_cast<const us4*>(vp);
        us4 r1 = *reinterpret_cast<const us4*>(vp + 4);
        us4 r2 = *reinterpret_cast<const us4*>(vp + 8);
        float v[12];
#pragma unroll
        for (int q = 0; q < 4; ++q) {
            v[q] = bf2f(r0[q]); v[4 + q] = bf2f(r1[q]); v[8 + q] = bf2f(r2[q]);
        }
#pragma unroll
        for (int d = 0; d < 4; ++d) {
            float a = 0.0f;
#pragma unroll
            for (int i = 0; i < 5; ++i) a = fmaf(wn[i], v[d + 2 + i], a);
            o[d][cc] = f2bf(a);
        }
    }
    unsigned short* obj = xb_img + ((size_t)(h0 + PD + j) * WP + PD + P) * CC
                                 + chalf * 16 + cl0;
#pragma unroll
    for (int d = 0; d < 4; ++d)
        *reinterpret_cast<us8*>(obj + d * CC) = o[d];
}

// ---------------------------------------------------------------------------
// Kernel 2: corner table (sorted by image offset) + pre-scaled B fragments.
// meta[37+e] = window-relative offset in 16B units: (Sy+7)*RUNITS+(Sx+8)*4.
// meta[74] = shifts fit |Sy|,|Sx|<=7.  (unchanged)
// ---------------------------------------------------------------------------
__global__ void wtrans_kernel(const float* __restrict__ wgt,
                              const float* __restrict__ sigma_p,
                              int* __restrict__ meta,
                              unsigned short* __restrict__ wb2) {
    __shared__ int   s_tap[36];
    __shared__ float s_w[36];
    __shared__ int   s_soff[36];
    __shared__ int   s_wrel[36];
    __shared__ int   s_n;
    const int t = threadIdx.x;

    if (t == 0) {
        const float UY[9] = {-0.70710678f, -1.0f, -0.70710678f, 0.0f, 0.0f, 0.0f,
                              0.70710678f,  1.0f,  0.70710678f};
        const float UX[9] = {-0.70710678f, 0.0f, 0.70710678f, -1.0f, 0.0f, 1.0f,
                             -0.70710678f, 0.0f, 0.70710678f};
        const int KYI[9] = {-1, -1, -1, 0, 0, 0, 1, 1, 1};
        const int KXI[9] = {-1, 0, 1, -1, 0, 1, -1, 0, 1};
        const float s6 = sigma_p[0] * 6.0f;
        int n = 0, ok = 1;
        for (int s_ = 0; s_ < 9; ++s_) {
            float offy = UY[s_] * s6, offx = UX[s_] * s6;
            float fy = floorf(offy), fx = floorf(offx);
            float ty = offy - fy,    tx = offx - fx;
            int sy = KYI[s_] + (int)fy;
            int sx = KXI[s_] + (int)fx;
            float wy[2] = {1.0f - ty, ty};
            float wx[2] = {1.0f - tx, tx};
            for (int dy = 0; dy < 2; ++dy)
                for (int dx = 0; dx < 2; ++dx) {
                    float wc = wy[dy] * wx[dx];
                    if (wc != 0.0f) {
                        const int syc = sy + dy, sxc = sx + dx;
                        s_tap[n]  = s_;
                        s_w[n]    = wc;
                        s_soff[n] = (syc * WP + sxc) * CC;
                        s_wrel[n] = (syc + 7) * RUNITS + (sxc + 8) * 4;
                        if (syc < -7 || syc > 7 || sxc < -7 || sxc > 7) ok = 0;
                        ++n;
                    }
                }
        }
        // insertion sort by soff (row-major (Sy,Sx) order; wrel co-sorts)
        for (int i = 1; i < n; ++i) {
            int ks = s_soff[i]; int kt = s_tap[i]; float kw = s_w[i]; int kr = s_wrel[i];
            int j = i - 1;
            while (j >= 0 && s_soff[j] > ks) {
                s_soff[j + 1] = s_soff[j]; s_tap[j + 1] = s_tap[j];
                s_w[j + 1] = s_w[j];       s_wrel[j + 1] = s_wrel[j];
                --j;
            }
            s_soff[j + 1] = ks; s_tap[j + 1] = kt; s_w[j + 1] = kw; s_wrel[j + 1] = kr;
        }
        if (blockIdx.x == 0) {
            meta[0] = n;
            for (int i = 0; i < n; ++i) { meta[1 + i] = s_soff[i]; meta[37 + i] = s_wrel[i]; }
            meta[74] = ok;
        }
        s_n = n;
    }
    __syncthreads();

    const int e = blockIdx.x;
    if (e >= s_n) return;
    for (int i = t; i < 1024; i += 256) {
        int j  = i & 7;
        int l  = (i >> 3) & 63;
        int nh = (i >> 9) & 1;
        int o  = nh * 16 + (l & 15);
        int c  = ((l >> 4) << 3) + j;
        wb2[e * 1024 + i] = f2bf(s_w[e] * wgt[(o * CC + c) * 9 + s_tap[e]]);
    }
}

// ---------------------------------------------------------------------------
// Kernel 3: LDS-staged stencil GEMM, flat window, global_load_lds staging,
// LDS ping-pong, 1024-thread block (R23 — unchanged).
// ---------------------------------------------------------------------------
#define LOADA(DST, E)                                                              \
    {                                                                              \
        const int ab_ = ubase + meta[37 + (E)];                                    \
        _Pragma("unroll")                                                          \
        for (int tx = 0; tx < 4; ++tx)                                             \
            DST[tx] = win[ab_ + tx * 64];                                          \
    }

#define MFMAA(SRC, E)                                                              \
    {                                                                              \
        const bf16x8 b0_ = *reinterpret_cast<const bf16x8*>(wb2 + (((E) * 2 + 0) * 64 + lane) * 8); \
        const bf16x8 b1_ = *reinterpret_cast<const bf16x8*>(wb2 + (((E) * 2 + 1) * 64 + lane) * 8); \
        _Pragma("unroll")                                                          \
        for (int tx = 0; tx < 4; ++tx) {                                           \
            acc[tx][0] = __builtin_amdgcn_mfma_f32_16x16x32_bf16(SRC[tx], b0_, acc[tx][0], 0, 0, 0); \
            acc[tx][1] = __builtin_amdgcn_mfma_f32_16x16x32_bf16(SRC[tx], b1_, acc[tx][1], 0, 0, 0); \
        }                                                                          \
    }

__global__ __launch_bounds__(1024, 4) void mix8_kernel(const unsigned short* __restrict__ xbt,
                                                       const int* __restrict__ meta,
                                                       const unsigned short* __restrict__ wb2,
                                                       float* __restrict__ out) {
    __shared__ bf16x8 win[WUNITS];           // 153,600 B, flat [row][px][ch]
    const int t    = threadIdx.x;
    const int lane = t & 63;
    const int wv   = t >> 6;                 // 0..15 = out row within band
    const int blk  = ((blockIdx.x & 7) << 7) + (blockIdx.x >> 3);  // 1024 blocks, chunk 128
    const int xs   = blk & 3;
    const int band = (blk >> 2) & 15;
    const int b    = blk >> 6;
    const int h0   = band << 4;
    const int x0   = xs << 6;
    const int mrow = lane & 15;
    const int cu   = lane >> 4;              // channel-unit 0..3
    const int ncorn = meta[0];
    const int ok    = meta[74];

    const unsigned short* img = xbt + (size_t)b * (HP * WP * CC);

    f32x4 acc[4][2];                         // [tx][half]
#pragma unroll
    for (int q = 0; q < 4; ++q) {
        acc[q][0] = (f32x4){0.f, 0.f, 0.f, 0.f};
        acc[q][1] = (f32x4){0.f, 0.f, 0.f, 0.f};
    }

    if (ok) {
        // ---- stage window rows h0+1..h0+30 (padded), px cells x0..x0+79 ----
        const us8* imgu  = reinterpret_cast<const us8*>(img);
        const int  gbase = ((h0 + 1) * WP + x0) * 4;       // 16B units
#pragma unroll
        for (int k = 0; k < 9; ++k) {
            const int i   = k * 1024 + t;
            const int row = i / RUNITS;
            const int u   = i - row * RUNITS;
            const us8* src = &imgu[gbase + row * (WP * 4) + u];
            __builtin_amdgcn_global_load_lds(
                (const __attribute__((address_space(1))) unsigned int*)src,
                (__attribute__((address_space(3))) unsigned int*)&win[i], 16, 0, 0);
        }
        if (t < 384) {  // tail 9216..9599: 6 full waves
            const int i   = 9216 + t;
            const int row = i / RUNITS;
            const int u   = i - row * RUNITS;
            const us8* src = &imgu[gbase + row * (WP * 4) + u];
            __builtin_amdgcn_global_load_lds(
                (const __attribute__((address_space(1))) unsigned int*)src,
                (__attribute__((address_space(3))) unsigned int*)&win[i], 16, 0, 0);
        }
        __syncthreads();

        // per-lane invariant base: out row wv -> window row wv (+7 via wrel)
        const int ubase = wv * RUNITS + mrow * 4 + cu;
        if (ncorn == NE21) {
            bf16x8 A0[4], A1[4];
            LOADA(A0, 0);
#pragma unroll
            for (int e = 0; e < 20; e += 2) {
                LOADA(A1, e + 1);
                MFMAA(A0, e);
                LOADA(A0, e + 2);        // e+2 <= 20 always in this loop
                MFMAA(A1, e + 1);
            }
            MFMAA(A0, 20);
        } else {
            for (int e = 0; e < ncorn; ++e) {
                const int ewr = meta[37 + e];
                const bf16x8 b0 = *reinterpret_cast<const bf16x8*>(wb2 + ((e * 2 + 0) * 64 + lane) * 8);
                const bf16x8 b1 = *reinterpret_cast<const bf16x8*>(wb2 + ((e * 2 + 1) * 64 + lane) * 8);
                const int abase = ubase + ewr;
#pragma unroll
                for (int tx = 0; tx < 4; ++tx) {
                    const bf16x8 a = win[abase + tx * 64];
                    acc[tx][0] = __builtin_amdgcn_mfma_f32_16x16x32_bf16(a, b0, acc[tx][0], 0, 0, 0);
                    acc[tx][1] = __builtin_amdgcn_mfma_f32_16x16x32_bf16(a, b1, acc[tx][1], 0, 0, 0);
                }
            }
        }
    } else {
        // generic fallback (any sigma): A straight from global
        const unsigned short* gb = img + ((size_t)(h0 + wv + PD) * WP + x0 + PD) * CC
                                       + mrow * CC + cu * 8;
        for (int e = 0; e < ncorn; ++e) {
            const int soff = meta[1 + e];
            const bf16x8 b0 = *reinterpret_cast<const bf16x8*>(wb2 + ((e * 2 + 0) * 64 + lane) * 8);
            const bf16x8 b1 = *reinterpret_cast<const bf16x8*>(wb2 + ((e * 2 + 1) * 64 + lane) * 8);
#pragma unroll
            for (int tx = 0; tx < 4; ++tx) {
                const bf16x8 a = *reinterpret_cast<const bf16x8*>(gb + soff + (size_t)tx * 16 * CC);
                acc[tx][0] = __builtin_amdgcn_mfma_f32_16x16x32_bf16(a, b0, acc[tx][0], 0, 0, 0);
                acc[tx][1] = __builtin_amdgcn_mfma_f32_16x16x32_bf16(a, b1, acc[tx][1], 0, 0, 0);
            }
        }
    }

    // D: out channel = lane&15 (+16 for half1), pixel = x0 + tx*16 + cu*4 + reg
    const int prow = cu << 2;
    float* opr = out + ((size_t)b * OO + (lane & 15)) * HW + (size_t)(h0 + wv) * WW + x0 + prow;
#pragma unroll
    for (int tx = 0; tx < 4; ++tx) {
        *reinterpret_cast<f32x4*>(opr + tx * 16) = acc[tx][0];
        *reinterpret_cast<f32x4*>(opr + tx * 16 + (size_t)16 * HW) = acc[tx][1];
    }
}

// ---------------------------------------------------------------------------
extern "C" void kernel_launch(void* const* d_in, const int* in_sizes, int n_in,
                              void* d_out, int out_size, void* d_ws, size_t ws_size,
                              hipStream_t stream) {
    const float* x     = (const float*)d_in[0];
    const float* sigma = (const float*)d_in[1];
    const float* wgt   = (const float*)d_in[2];
    float* out = (float*)d_out;

    // ws layout: [ meta: 128 ints ][ wb2: 36*1024 bf16 ] (128 KB reserved)
    //            [ xbt: BB*HP*WP*CC bf16 padded image ]
    int* meta           = (int*)d_ws;
    unsigned short* wb2 = (unsigned short*)((char*)d_ws + 512);
    unsigned short* xbt = (unsigned short*)((char*)d_ws + 131072);

    wtrans_kernel<<<36, 256, 0, stream>>>(wgt, sigma, meta, wb2);
    blur_t_kernel<<<BB * 256, 256, 0, stream>>>(x, sigma, xbt);
    mix8_kernel<<<BB * 64, 1024, 0, stream>>>(xbt, meta, wb2, out);
}

// Round 27
// 130.870 us; speedup vs baseline: 1.0315x; 1.0315x over previous
//
#include <hip/hip_runtime.h>
#include <math.h>

#define BB 16
#define CC 32
#define OO 32
#define HH 256
#define WW 256
#define HW (HH * WW)
#define PD 8
#define HP (HH + 2 * PD)      // 272
#define WP (WW + 2 * PD)      // 272
#define NEMAX 36
#define NE21 21               // corner count for sigma=1-class offsets

// mix8 window geometry: block = 16 rows x 64 px; shifts |Sy|,|Sx| <= 7
#define WROWS 30              // 16 + 2*7
#define WCOLS 80              // 64 + 2*7
#define RUNITS 320            // 16B units per window row (80 px * 4)
#define WUNITS (WROWS * RUNITS)   // 9600 units = 153,600 B

typedef __attribute__((ext_vector_type(8))) short bf16x8;
typedef __attribute__((ext_vector_type(4))) float f32x4;
typedef __attribute__((ext_vector_type(4))) unsigned short us4;
typedef __attribute__((ext_vector_type(8))) unsigned short us8;

__device__ __forceinline__ unsigned short f2bf(float f) {
    unsigned u = __float_as_uint(f);
    u += 0x7fffu + ((u >> 16) & 1u);     // round-to-nearest-even
    return (unsigned short)(u >> 16);
}
__device__ __forceinline__ float bf2f(unsigned short v) {
    return __uint_as_float((unsigned)v << 16);
}

__device__ __forceinline__ void blur_wn(const float* sigma_p, float* wn) {
    const float sigma = sigma_p[0];
    const float inv2s2 = 1.0f / (2.0f * sigma * sigma);
    float e[5], s = 0.0f;
#pragma unroll
    for (int i = 0; i < 5; ++i) {
        float d = (float)(i - 2);
        e[i] = expf(-(d * d) * inv2s2);
        s += e[i];
    }
    const float inv_s = 1.0f / s;
#pragma unroll
    for (int i = 0; i < 5; ++i) wn[i] = e[i] * inv_s;
}

// ---------------------------------------------------------------------------
// Kernel 1: 5x5 separable Gaussian blur -> zero-padded channels-last bf16
//   xbt[b][y=h+PD][x=w+PD][c].
// R27: block = 512 thr, 2 rows x ALL 32 channels (was 16). Phase-2 regrouped
// so 4 consecutive lanes supply a FULL 64B channel line per px — previous
// 16-ch blocks wrote only 32B of each line (partial-line writebacks unless
// the sibling block's stores happened to coincide in L2). Per-thread work
// identical; LDS 34.3KB -> 4 blocks/CU = 32 waves.
// ---------------------------------------------------------------------------
#define LOADROWS(DST, IT)                                                         \
    {                                                                             \
        const int cl_ = ((IT) << 3) + wv;                                         \
        const float* xc_ = x + ((size_t)(b * CC + cl_) * HH) * WW + 4 * g;        \
        _Pragma("unroll")                                                         \
        for (int k = 0; k < 6; ++k) {                                             \
            const int r_ = h0 - 2 + k;                                            \
            DST[k] = (r_ >= 0 && r_ < HH)                                         \
                   ? *reinterpret_cast<const f32x4*>(xc_ + r_ * WW)               \
                   : (f32x4){0.f, 0.f, 0.f, 0.f};                                 \
        }                                                                         \
    }

#define VBLUR(SRC, IT)                                                            \
    {                                                                             \
        const int cl_ = ((IT) << 3) + wv;                                         \
        _Pragma("unroll")                                                         \
        for (int j = 0; j < 2; ++j) {                                             \
            f32x4 a_ = {0.f, 0.f, 0.f, 0.f};                                      \
            _Pragma("unroll")                                                     \
            for (int i = 0; i < 5; ++i) {                                         \
                a_[0] = fmaf(wn[i], SRC[j + i][0], a_[0]);                        \
                a_[1] = fmaf(wn[i], SRC[j + i][1], a_[1]);                        \
                a_[2] = fmaf(wn[i], SRC[j + i][2], a_[2]);                        \
                a_[3] = fmaf(wn[i], SRC[j + i][3], a_[3]);                        \
            }                                                                     \
            us4 bv_;                                                              \
            bv_[0] = f2bf(a_[0]); bv_[1] = f2bf(a_[1]);                           \
            bv_[2] = f2bf(a_[2]); bv_[3] = f2bf(a_[3]);                           \
            *reinterpret_cast<us4*>(&vb[cl_][j][4 + 4 * g]) = bv_;                \
        }                                                                         \
    }

__global__ __launch_bounds__(512) void blur_t_kernel(const float* __restrict__ x,
                                                     const float* __restrict__ sigma_p,
                                                     unsigned short* __restrict__ xbt) {
    __shared__ __align__(16) unsigned short vb[32][2][268];   // 34,304 B
    const int t    = threadIdx.x;
    const int blk  = ((blockIdx.x & 7) << 8) + (blockIdx.x >> 3);  // 2048, chunk 256
    const int band = blk & 127;
    const int b    = blk >> 7;
    const int h0   = band << 1;

    float wn[5];
    blur_wn(sigma_p, wn);

    unsigned short* xb_img = xbt + (size_t)b * (HP * WP * CC);

    // ---- halo zeroing (all 32 channels now) ----
    const us8 z8 = {0, 0, 0, 0, 0, 0, 0, 0};
    if (t < 128) {   // side halos of own 2 padded rows: 2 x 16px x 4 octets
        const int j  = t >> 6;
        const int px = (t >> 2) & 15;
        const int ch = t & 3;
        const int xx = (px < PD) ? px : px + WW;
        *reinterpret_cast<us8*>(xb_img + ((size_t)(h0 + PD + j) * WP + xx) * CC + ch * 8) = z8;
    }
    if (h0 < PD) {           // bands 0..3: zero full padded rows y' = h0, h0+1
#pragma unroll
        for (int j2 = 0; j2 < 2; ++j2) {
            unsigned short* dst = xb_img + (size_t)(h0 + j2) * WP * CC;
            for (int i = t; i < (WP * CC) / 8; i += 512)
                *reinterpret_cast<us8*>(dst + i * 8) = z8;
        }
    }
#pragma unroll
    for (int j2 = 0; j2 < 2; ++j2) {     // bottom padded rows
        if (h0 + j2 >= HH - PD) {
            unsigned short* dst = xb_img + (size_t)(h0 + j2 + 2 * PD) * WP * CC;
            for (int i = t; i < (WP * CC) / 8; i += 512)
                *reinterpret_cast<us8*>(dst + i * 8) = z8;
        }
    }

    // edge zero cols: px {-2,-1,256,257} -> vb cols {2,3,260,261}: 32*2*4 = 256
    if (t < 256) {
        const int cl = t >> 3;
        const int j  = (t >> 2) & 1;
        const int e_ = t & 3;
        const int idx = (e_ < 2) ? (2 + e_) : (258 + e_);
        vb[cl][j][idx] = 0;
    }

    // ---- phase 1: vertical blur, ALL loads issued before any use ----
    const int g  = t & 63;          // px group of 4
    const int wv = t >> 6;          // wave 0..7
    {
        f32x4 V[4][6];
#pragma unroll
        for (int it = 0; it < 4; ++it) LOADROWS(V[it], it);
#pragma unroll
        for (int it = 0; it < 4; ++it) VBLUR(V[it], it);
    }
    __syncthreads();

    // ---- phase 2: horizontal blur, 8 ch x 4 px x 1 row per thread ----
    // t -> (ch-octet cu4 = t&3, px-quad p4 = (t>>2)&63, row j = t>>8):
    // 4 consecutive lanes cover the full 64B line of each px.
    const int cu4 = t & 3;
    const int p4  = (t >> 2) & 63;
    const int j   = t >> 8;
    const int P   = p4 << 2;
    const int cl0 = cu4 << 3;

    us8 o[4];                        // o[d] = 8 channels at px P+d
#pragma unroll
    for (int cc = 0; cc < 8; ++cc) {
        const unsigned short* vp = &vb[cl0 + cc][j][P];
        us4 r0 = *reinterpret_cast<const us4*>(vp);
        us4 r1 = *reinterpret_cast<const us4*>(vp + 4);
        us4 r2 = *reinterpret_cast<const us4*>(vp + 8);
        float v[12];
#pragma unroll
        for (int q = 0; q < 4; ++q) {
            v[q] = bf2f(r0[q]); v[4 + q] = bf2f(r1[q]); v[8 + q] = bf2f(r2[q]);
        }
#pragma unroll
        for (int d = 0; d < 4; ++d) {
            float a = 0.0f;
#pragma unroll
            for (int i = 0; i < 5; ++i) a = fmaf(wn[i], v[d + 2 + i], a);
            o[d][cc] = f2bf(a);
        }
    }
    unsigned short* obj = xb_img + ((size_t)(h0 + PD + j) * WP + PD + P) * CC + cl0;
#pragma unroll
    for (int d = 0; d < 4; ++d)
        *reinterpret_cast<us8*>(obj + d * CC) = o[d];
}

// ---------------------------------------------------------------------------
// Kernel 2: corner table (sorted by image offset) + pre-scaled B fragments.
// meta[37+e] = window-relative offset in 16B units: (Sy+7)*RUNITS+(Sx+8)*4.
// meta[74] = shifts fit |Sy|,|Sx|<=7.  (unchanged)
// ---------------------------------------------------------------------------
__global__ void wtrans_kernel(const float* __restrict__ wgt,
                              const float* __restrict__ sigma_p,
                              int* __restrict__ meta,
                              unsigned short* __restrict__ wb2) {
    __shared__ int   s_tap[36];
    __shared__ float s_w[36];
    __shared__ int   s_soff[36];
    __shared__ int   s_wrel[36];
    __shared__ int   s_n;
    const int t = threadIdx.x;

    if (t == 0) {
        const float UY[9] = {-0.70710678f, -1.0f, -0.70710678f, 0.0f, 0.0f, 0.0f,
                              0.70710678f,  1.0f,  0.70710678f};
        const float UX[9] = {-0.70710678f, 0.0f, 0.70710678f, -1.0f, 0.0f, 1.0f,
                             -0.70710678f, 0.0f, 0.70710678f};
        const int KYI[9] = {-1, -1, -1, 0, 0, 0, 1, 1, 1};
        const int KXI[9] = {-1, 0, 1, -1, 0, 1, -1, 0, 1};
        const float s6 = sigma_p[0] * 6.0f;
        int n = 0, ok = 1;
        for (int s_ = 0; s_ < 9; ++s_) {
            float offy = UY[s_] * s6, offx = UX[s_] * s6;
            float fy = floorf(offy), fx = floorf(offx);
            float ty = offy - fy,    tx = offx - fx;
            int sy = KYI[s_] + (int)fy;
            int sx = KXI[s_] + (int)fx;
            float wy[2] = {1.0f - ty, ty};
            float wx[2] = {1.0f - tx, tx};
            for (int dy = 0; dy < 2; ++dy)
                for (int dx = 0; dx < 2; ++dx) {
                    float wc = wy[dy] * wx[dx];
                    if (wc != 0.0f) {
                        const int syc = sy + dy, sxc = sx + dx;
                        s_tap[n]  = s_;
                        s_w[n]    = wc;
                        s_soff[n] = (syc * WP + sxc) * CC;
                        s_wrel[n] = (syc + 7) * RUNITS + (sxc + 8) * 4;
                        if (syc < -7 || syc > 7 || sxc < -7 || sxc > 7) ok = 0;
                        ++n;
                    }
                }
        }
        // insertion sort by soff (row-major (Sy,Sx) order; wrel co-sorts)
        for (int i = 1; i < n; ++i) {
            int ks = s_soff[i]; int kt = s_tap[i]; float kw = s_w[i]; int kr = s_wrel[i];
            int j = i - 1;
            while (j >= 0 && s_soff[j] > ks) {
                s_soff[j + 1] = s_soff[j]; s_tap[j + 1] = s_tap[j];
                s_w[j + 1] = s_w[j];       s_wrel[j + 1] = s_wrel[j];
                --j;
            }
            s_soff[j + 1] = ks; s_tap[j + 1] = kt; s_w[j + 1] = kw; s_wrel[j + 1] = kr;
        }
        if (blockIdx.x == 0) {
            meta[0] = n;
            for (int i = 0; i < n; ++i) { meta[1 + i] = s_soff[i]; meta[37 + i] = s_wrel[i]; }
            meta[74] = ok;
        }
        s_n = n;
    }
    __syncthreads();

    const int e = blockIdx.x;
    if (e >= s_n) return;
    for (int i = t; i < 1024; i += 256) {
        int j  = i & 7;
        int l  = (i >> 3) & 63;
        int nh = (i >> 9) & 1;
        int o  = nh * 16 + (l & 15);
        int c  = ((l >> 4) << 3) + j;
        wb2[e * 1024 + i] = f2bf(s_w[e] * wgt[(o * CC + c) * 9 + s_tap[e]]);
    }
}

// ---------------------------------------------------------------------------
// Kernel 3: LDS-staged stencil GEMM, flat window, global_load_lds staging,
// LDS ping-pong, 1024-thread block (R23 — unchanged).
// ---------------------------------------------------------------------------
#define LOADA(DST, E)                                                              \
    {                                                                              \
        const int ab_ = ubase + meta[37 + (E)];                                    \
        _Pragma("unroll")                                                          \
        for (int tx = 0; tx < 4; ++tx)                                             \
            DST[tx] = win[ab_ + tx * 64];                                          \
    }

#define MFMAA(SRC, E)                                                              \
    {                                                                              \
        const bf16x8 b0_ = *reinterpret_cast<const bf16x8*>(wb2 + (((E) * 2 + 0) * 64 + lane) * 8); \
        const bf16x8 b1_ = *reinterpret_cast<const bf16x8*>(wb2 + (((E) * 2 + 1) * 64 + lane) * 8); \
        _Pragma("unroll")                                                          \
        for (int tx = 0; tx < 4; ++tx) {                                           \
            acc[tx][0] = __builtin_amdgcn_mfma_f32_16x16x32_bf16(SRC[tx], b0_, acc[tx][0], 0, 0, 0); \
            acc[tx][1] = __builtin_amdgcn_mfma_f32_16x16x32_bf16(SRC[tx], b1_, acc[tx][1], 0, 0, 0); \
        }                                                                          \
    }

__global__ __launch_bounds__(1024, 4) void mix8_kernel(const unsigned short* __restrict__ xbt,
                                                       const int* __restrict__ meta,
                                                       const unsigned short* __restrict__ wb2,
                                                       float* __restrict__ out) {
    __shared__ bf16x8 win[WUNITS];           // 153,600 B, flat [row][px][ch]
    const int t    = threadIdx.x;
    const int lane = t & 63;
    const int wv   = t >> 6;                 // 0..15 = out row within band
    const int blk  = ((blockIdx.x & 7) << 7) + (blockIdx.x >> 3);  // 1024 blocks, chunk 128
    const int xs   = blk & 3;
    const int band = (blk >> 2) & 15;
    const int b    = blk >> 6;
    const int h0   = band << 4;
    const int x0   = xs << 6;
    const int mrow = lane & 15;
    const int cu   = lane >> 4;              // channel-unit 0..3
    const int ncorn = meta[0];
    const int ok    = meta[74];

    const unsigned short* img = xbt + (size_t)b * (HP * WP * CC);

    f32x4 acc[4][2];                         // [tx][half]
#pragma unroll
    for (int q = 0; q < 4; ++q) {
        acc[q][0] = (f32x4){0.f, 0.f, 0.f, 0.f};
        acc[q][1] = (f32x4){0.f, 0.f, 0.f, 0.f};
    }

    if (ok) {
        // ---- stage window rows h0+1..h0+30 (padded), px cells x0..x0+79 ----
        const us8* imgu  = reinterpret_cast<const us8*>(img);
        const int  gbase = ((h0 + 1) * WP + x0) * 4;       // 16B units
#pragma unroll
        for (int k = 0; k < 9; ++k) {
            const int i   = k * 1024 + t;
            const int row = i / RUNITS;
            const int u   = i - row * RUNITS;
            const us8* src = &imgu[gbase + row * (WP * 4) + u];
            __builtin_amdgcn_global_load_lds(
                (const __attribute__((address_space(1))) unsigned int*)src,
                (__attribute__((address_space(3))) unsigned int*)&win[i], 16, 0, 0);
        }
        if (t < 384) {  // tail 9216..9599: 6 full waves
            const int i   = 9216 + t;
            const int row = i / RUNITS;
            const int u   = i - row * RUNITS;
            const us8* src = &imgu[gbase + row * (WP * 4) + u];
            __builtin_amdgcn_global_load_lds(
                (const __attribute__((address_space(1))) unsigned int*)src,
                (__attribute__((address_space(3))) unsigned int*)&win[i], 16, 0, 0);
        }
        __syncthreads();

        // per-lane invariant base: out row wv -> window row wv (+7 via wrel)
        const int ubase = wv * RUNITS + mrow * 4 + cu;
        if (ncorn == NE21) {
            bf16x8 A0[4], A1[4];
            LOADA(A0, 0);
#pragma unroll
            for (int e = 0; e < 20; e += 2) {
                LOADA(A1, e + 1);
                MFMAA(A0, e);
                LOADA(A0, e + 2);        // e+2 <= 20 always in this loop
                MFMAA(A1, e + 1);
            }
            MFMAA(A0, 20);
        } else {
            for (int e = 0; e < ncorn; ++e) {
                const int ewr = meta[37 + e];
                const bf16x8 b0 = *reinterpret_cast<const bf16x8*>(wb2 + ((e * 2 + 0) * 64 + lane) * 8);
                const bf16x8 b1 = *reinterpret_cast<const bf16x8*>(wb2 + ((e * 2 + 1) * 64 + lane) * 8);
                const int abase = ubase + ewr;
#pragma unroll
                for (int tx = 0; tx < 4; ++tx) {
                    const bf16x8 a = win[abase + tx * 64];
                    acc[tx][0] = __builtin_amdgcn_mfma_f32_16x16x32_bf16(a, b0, acc[tx][0], 0, 0, 0);
                    acc[tx][1] = __builtin_amdgcn_mfma_f32_16x16x32_bf16(a, b1, acc[tx][1], 0, 0, 0);
                }
            }
        }
    } else {
        // generic fallback (any sigma): A straight from global
        const unsigned short* gb = img + ((size_t)(h0 + wv + PD) * WP + x0 + PD) * CC
                                       + mrow * CC + cu * 8;
        for (int e = 0; e < ncorn; ++e) {
            const int soff = meta[1 + e];
            const bf16x8 b0 = *reinterpret_cast<const bf16x8*>(wb2 + ((e * 2 + 0) * 64 + lane) * 8);
            const bf16x8 b1 = *reinterpret_cast<const bf16x8*>(wb2 + ((e * 2 + 1) * 64 + lane) * 8);
#pragma unroll
            for (int tx = 0; tx < 4; ++tx) {
                const bf16x8 a = *reinterpret_cast<const bf16x8*>(gb + soff + (size_t)tx * 16 * CC);
                acc[tx][0] = __builtin_amdgcn_mfma_f32_16x16x32_bf16(a, b0, acc[tx][0], 0, 0, 0);
                acc[tx][1] = __builtin_amdgcn_mfma_f32_16x16x32_bf16(a, b1, acc[tx][1], 0, 0, 0);
            }
        }
    }

    // D: out channel = lane&15 (+16 for half1), pixel = x0 + tx*16 + cu*4 + reg
    const int prow = cu << 2;
    float* opr = out + ((size_t)b * OO + (lane & 15)) * HW + (size_t)(h0 + wv) * WW + x0 + prow;
#pragma unroll
    for (int tx = 0; tx < 4; ++tx) {
        *reinterpret_cast<f32x4*>(opr + tx * 16) = acc[tx][0];
        *reinterpret_cast<f32x4*>(opr + tx * 16 + (size_t)16 * HW) = acc[tx][1];
    }
}

// ---------------------------------------------------------------------------
extern "C" void kernel_launch(void* const* d_in, const int* in_sizes, int n_in,
                              void* d_out, int out_size, void* d_ws, size_t ws_size,
                              hipStream_t stream) {
    const float* x     = (const float*)d_in[0];
    const float* sigma = (const float*)d_in[1];
    const float* wgt   = (const float*)d_in[2];
    float* out = (float*)d_out;

    // ws layout: [ meta: 128 ints ][ wb2: 36*1024 bf16 ] (128 KB reserved)
    //            [ xbt: BB*HP*WP*CC bf16 padded image ]
    int* meta           = (int*)d_ws;
    unsigned short* wb2 = (unsigned short*)((char*)d_ws + 512);
    unsigned short* xbt = (unsigned short*)((char*)d_ws + 131072);

    wtrans_kernel<<<36, 256, 0, stream>>>(wgt, sigma, meta, wb2);
    blur_t_kernel<<<BB * 128, 512, 0, stream>>>(x, sigma, xbt);
    mix8_kernel<<<BB * 64, 1024, 0, stream>>>(xbt, meta, wb2, out);
}